// Round 5
// baseline (95.831 us; speedup 1.0000x reference)
//
#include <hip/hip_runtime.h>

// N = 16,777,216 fp32 probabilities + int32 {0,1} targets.
//   count      = #{ p > 0.5 && t == 0 }
//   out        = mean( -(t*log p + (1-t)*log(1-p)) ) * (1 + 0.1*count)
//
// R1-R3: 79/65/62 us — plateau was f64 atomicAdd = CAS retry loop, 2048
//        blocks contending one address.
// R4:    atomics removed (disjoint partials + tiny 2nd kernel): 31 us.
//        Main pass now ~5 TB/s; residual = 2nd-kernel launch + gap + tail.
// R5:    fuse final reduction via threadfence-reduction: last block (by
//        global ticket) reduces the 2048 partials. Counter zeroed per call
//        by 4-byte hipMemsetAsync (d_ws is poisoned 0xAA after the
//        correctness call, so it must be re-inited every launch).
//        Cross-XCD safety: agent-scope __hip_atomic_* stores/loads +
//        __threadfence release/acquire — no reliance on L2 coherence.

#define N_ELEM  16777216
#define N_VEC4  (N_ELEM / 4)       // 4,194,304
#define BLOCKS  2048
#define TPB     256
#define NTHREAD (BLOCKS * TPB)     // 524,288
#define NITER   (N_VEC4 / NTHREAD) // exactly 8

// d_ws layout:
//   [0      .. 16384)  double psum[2048]
//   [16384  .. 24576)  uint   pcnt[2048]
//   [24576  .. 24580)  uint   ticket counter (memset to 0 each call)
#define WS_PCNT_OFF 16384
#define WS_CTR_OFF  24576

__global__ __launch_bounds__(TPB, 4) void cl_fused(
    const float4* __restrict__ p4,
    const int4*   __restrict__ t4,
    double*       __restrict__ psum,
    unsigned int* __restrict__ pcnt,
    unsigned int* __restrict__ ctr,
    float*        __restrict__ out)
{
    const int tid = blockIdx.x * TPB + threadIdx.x;

    float4 p[NITER];
    int4   t[NITER];
    #pragma unroll
    for (int j = 0; j < NITER; ++j) {
        p[j] = p4[tid + j * NTHREAD];
        t[j] = t4[tid + j * NTHREAD];
    }
    __builtin_amdgcn_sched_barrier(0);

    float        lsum = 0.0f;
    unsigned int lcnt = 0u;
    #pragma unroll
    for (int j = 0; j < NITER; ++j) {
        lsum += __logf(t[j].x ? p[j].x : 1.0f - p[j].x);
        lsum += __logf(t[j].y ? p[j].y : 1.0f - p[j].y);
        lsum += __logf(t[j].z ? p[j].z : 1.0f - p[j].z);
        lsum += __logf(t[j].w ? p[j].w : 1.0f - p[j].w);
        lcnt += (unsigned int)((p[j].x > 0.5f) & (t[j].x == 0));
        lcnt += (unsigned int)((p[j].y > 0.5f) & (t[j].y == 0));
        lcnt += (unsigned int)((p[j].z > 0.5f) & (t[j].z == 0));
        lcnt += (unsigned int)((p[j].w > 0.5f) & (t[j].w == 0));
    }
    lsum = -lsum;

    // 64-lane wave reduction
    #pragma unroll
    for (int off = 32; off > 0; off >>= 1) {
        lsum += __shfl_down(lsum, off);
        lcnt += __shfl_down(lcnt, off);
    }

    // block reduction across 4 waves
    __shared__ float        s_sum[4];
    __shared__ unsigned int s_cnt[4];
    __shared__ unsigned int s_ticket;
    const int wave = threadIdx.x >> 6;
    const int lane = threadIdx.x & 63;
    if (lane == 0) { s_sum[wave] = lsum; s_cnt[wave] = lcnt; }
    __syncthreads();

    if (threadIdx.x == 0) {
        const double       bs = (double)(s_sum[0] + s_sum[1] + s_sum[2] + s_sum[3]);
        const unsigned int bc = s_cnt[0] + s_cnt[1] + s_cnt[2] + s_cnt[3];
        // agent-scope stores: visible device-wide regardless of XCD L2s
        __hip_atomic_store(&psum[blockIdx.x], bs, __ATOMIC_RELAXED, __HIP_MEMORY_SCOPE_AGENT);
        __hip_atomic_store(&pcnt[blockIdx.x], bc, __ATOMIC_RELAXED, __HIP_MEMORY_SCOPE_AGENT);
        __threadfence();                       // release
        s_ticket = atomicAdd(ctr, 1u);         // device-scope
    }
    __syncthreads();

    if (s_ticket == BLOCKS - 1) {
        // last block to arrive: every other block's partials are published
        __threadfence();                       // acquire
        double       s = 0.0;
        unsigned int c = 0u;
        #pragma unroll
        for (int j = 0; j < BLOCKS / TPB; ++j) {   // 8 partials per thread
            s += __hip_atomic_load(&psum[threadIdx.x + j * TPB],
                                   __ATOMIC_RELAXED, __HIP_MEMORY_SCOPE_AGENT);
            c += __hip_atomic_load(&pcnt[threadIdx.x + j * TPB],
                                   __ATOMIC_RELAXED, __HIP_MEMORY_SCOPE_AGENT);
        }
        #pragma unroll
        for (int off = 32; off > 0; off >>= 1) {
            s += __shfl_down(s, off);
            c += __shfl_down(c, off);
        }
        __shared__ double       fs[4];
        __shared__ unsigned int fc[4];
        if (lane == 0) { fs[wave] = s; fc[wave] = c; }
        __syncthreads();
        if (threadIdx.x == 0) {
            const double       tot = fs[0] + fs[1] + fs[2] + fs[3];
            const unsigned int tc  = fc[0] + fc[1] + fc[2] + fc[3];
            out[0] = (float)((tot * (1.0 / (double)N_ELEM)) * (1.0 + 0.1 * (double)tc));
        }
    }
}

extern "C" void kernel_launch(void* const* d_in, const int* in_sizes, int n_in,
                              void* d_out, int out_size, void* d_ws, size_t ws_size,
                              hipStream_t stream) {
    const float4* p4 = (const float4*)d_in[0];
    const int4*   t4 = (const int4*)d_in[1];
    float*        out = (float*)d_out;

    double*       psum = (double*)d_ws;
    unsigned int* pcnt = (unsigned int*)((char*)d_ws + WS_PCNT_OFF);
    unsigned int* ctr  = (unsigned int*)((char*)d_ws + WS_CTR_OFF);

    // ticket counter must be 0 at kernel start, every call (ws is poisoned
    // once after the correctness call; nothing re-inits between replays).
    hipMemsetAsync(ctr, 0, sizeof(unsigned int), stream);

    cl_fused<<<BLOCKS, TPB, 0, stream>>>(p4, t4, psum, pcnt, ctr, out);
}

// Round 6
// 28.011 us; speedup vs baseline: 3.4212x; 3.4212x over previous
//
#include <hip/hip_runtime.h>

// N = 16,777,216 fp32 probabilities + int32 {0,1} targets.
//   count      = #{ p > 0.5 && t == 0 }
//   out        = mean( -(t*log p + (1-t)*log(1-p)) ) * (1 + 0.1*count)
//
// R1-R3: 79/65/62 us — plateau was f64 atomicAdd (CAS retry loop).
// R4:    disjoint partials + tiny 2nd kernel, no atomics: 30.9 us.
// R5:    fused ticket + __threadfence regressed to 96 us — per-block
//        device fences emit buffer_wbl2 (whole-L2 writeback) x2048. NEVER
//        put __threadfence in a per-block epilogue on gfx950. Reverted.
// R6:    R4 base + NON-TEMPORAL loads (nt flag): 134 MB of no-reuse
//        streams thrash the 32 MiB L2 (alloc+evict every line for zero
//        benefit). nt bypasses L2 retention. Single-variable change.

#define N_ELEM  16777216
#define N_VEC4  (N_ELEM / 4)       // 4,194,304
#define BLOCKS  2048
#define TPB     256
#define NTHREAD (BLOCKS * TPB)     // 524,288
#define NITER   (N_VEC4 / NTHREAD) // exactly 8

typedef float f4v __attribute__((ext_vector_type(4)));
typedef int   i4v __attribute__((ext_vector_type(4)));

// d_ws layout: [0 .. 16384) double psum[2048]; [16384 .. 24576) uint pcnt[2048]
#define WS_PCNT_OFF 16384

__global__ __launch_bounds__(TPB, 4) void cl_reduce(
    const f4v* __restrict__ p4,
    const i4v* __restrict__ t4,
    double*       __restrict__ psum,
    unsigned int* __restrict__ pcnt)
{
    const int tid = blockIdx.x * TPB + threadIdx.x;

    f4v p[NITER];
    i4v t[NITER];
    #pragma unroll
    for (int j = 0; j < NITER; ++j) {
        p[j] = __builtin_nontemporal_load(&p4[tid + j * NTHREAD]);
        t[j] = __builtin_nontemporal_load(&t4[tid + j * NTHREAD]);
    }
    __builtin_amdgcn_sched_barrier(0);

    float        lsum = 0.0f;
    unsigned int lcnt = 0u;
    #pragma unroll
    for (int j = 0; j < NITER; ++j) {
        lsum += __logf(t[j][0] ? p[j][0] : 1.0f - p[j][0]);
        lsum += __logf(t[j][1] ? p[j][1] : 1.0f - p[j][1]);
        lsum += __logf(t[j][2] ? p[j][2] : 1.0f - p[j][2]);
        lsum += __logf(t[j][3] ? p[j][3] : 1.0f - p[j][3]);
        lcnt += (unsigned int)((p[j][0] > 0.5f) & (t[j][0] == 0));
        lcnt += (unsigned int)((p[j][1] > 0.5f) & (t[j][1] == 0));
        lcnt += (unsigned int)((p[j][2] > 0.5f) & (t[j][2] == 0));
        lcnt += (unsigned int)((p[j][3] > 0.5f) & (t[j][3] == 0));
    }
    lsum = -lsum;

    // 64-lane wave reduction
    #pragma unroll
    for (int off = 32; off > 0; off >>= 1) {
        lsum += __shfl_down(lsum, off);
        lcnt += __shfl_down(lcnt, off);
    }

    // block reduction across 4 waves -> ONE disjoint store per block, no atomics
    __shared__ float        s_sum[4];
    __shared__ unsigned int s_cnt[4];
    const int wave = threadIdx.x >> 6;
    const int lane = threadIdx.x & 63;
    if (lane == 0) { s_sum[wave] = lsum; s_cnt[wave] = lcnt; }
    __syncthreads();
    if (threadIdx.x == 0) {
        psum[blockIdx.x] = (double)(s_sum[0] + s_sum[1] + s_sum[2] + s_sum[3]);
        pcnt[blockIdx.x] = s_cnt[0] + s_cnt[1] + s_cnt[2] + s_cnt[3];
    }
}

__global__ __launch_bounds__(TPB) void cl_final(
    const double*       __restrict__ psum,
    const unsigned int* __restrict__ pcnt,
    float*              __restrict__ out)
{
    double       s = 0.0;
    unsigned int c = 0u;
    #pragma unroll
    for (int j = 0; j < BLOCKS / TPB; ++j) {   // 8 partials per thread
        s += psum[threadIdx.x + j * TPB];
        c += pcnt[threadIdx.x + j * TPB];
    }
    #pragma unroll
    for (int off = 32; off > 0; off >>= 1) {
        s += __shfl_down(s, off);
        c += __shfl_down(c, off);
    }
    __shared__ double       ss[4];
    __shared__ unsigned int sc[4];
    const int wave = threadIdx.x >> 6;
    const int lane = threadIdx.x & 63;
    if (lane == 0) { ss[wave] = s; sc[wave] = c; }
    __syncthreads();
    if (threadIdx.x == 0) {
        const double       tot = ss[0] + ss[1] + ss[2] + ss[3];
        const unsigned int tc  = sc[0] + sc[1] + sc[2] + sc[3];
        out[0] = (float)((tot * (1.0 / (double)N_ELEM)) * (1.0 + 0.1 * (double)tc));
    }
}

extern "C" void kernel_launch(void* const* d_in, const int* in_sizes, int n_in,
                              void* d_out, int out_size, void* d_ws, size_t ws_size,
                              hipStream_t stream) {
    const f4v* p4 = (const f4v*)d_in[0];
    const i4v* t4 = (const i4v*)d_in[1];
    float*     out = (float*)d_out;

    double*       psum = (double*)d_ws;
    unsigned int* pcnt = (unsigned int*)((char*)d_ws + WS_PCNT_OFF);

    cl_reduce<<<BLOCKS, TPB, 0, stream>>>(p4, t4, psum, pcnt);
    cl_final<<<1, TPB, 0, stream>>>(psum, pcnt, out);
}